// Round 9
// baseline (595.320 us; speedup 1.0000x reference)
//
#include <hip/hip_runtime.h>

// Content_SA: instance-norm -> f/g/h 1x1 convs -> attention(QK^T softmax, PV) -> o conv + residual.
// B=4, C=512, H=W=64 (N=4096).
// Algebra: energy[n,m] = xn(n)^T M xn(m) + u[m] (+ query-const, cancels in softmax), M = f_w^T g_w (fp32).
// Precision: M,Z,xn,V all f16 (single rounding from fp32-grade values); softmax fp32.
// Flash v6: 256-thread blocks (4 waves), q=32/block, 512 blocks -> 2 blocks/CU ANTI-PHASE
// (no cross-block barriers -> one block's QK overlaps the other's drain/softmax; m97 model).
// K 64KB single-buffer; stage issued after B2 (all K reads done); vpre1 issued BEFORE stage
// so no consumer ever drains the in-flight stage (R7 ordered-vmcnt lesson).

typedef __bf16 bf16_t;
typedef _Float16 f16_t;
typedef _Float16 f16x8 __attribute__((ext_vector_type(8)));
typedef float f32x4 __attribute__((ext_vector_type(4)));

#define LOG2E 1.44269504088896340736f

__device__ __forceinline__ void gload16(const void* g, void* l) {
  __builtin_amdgcn_global_load_lds(
      (const __attribute__((address_space(1))) void*)g,
      (__attribute__((address_space(3))) void*)l, 16, 0, 0);
}

#define WAITV10() asm volatile("s_waitcnt vmcnt(10)" ::: "memory")
#define WAITL() asm volatile("s_waitcnt lgkmcnt(0)" ::: "memory")
#define SB() __builtin_amdgcn_s_barrier()
#define SCHED0() __builtin_amdgcn_sched_barrier(0)

// ---------------- instance-norm statistics ----------------
__global__ void __launch_bounds__(256) stats_k(const float* __restrict__ x,
                                               float* __restrict__ mu,
                                               float* __restrict__ rs) {
  const int bc = blockIdx.x;
  const float4* row = (const float4*)(x + (size_t)bc * 4096);
  float s = 0.f, ss = 0.f;
  for (int i = threadIdx.x; i < 1024; i += 256) {
    float4 v = row[i];
    s += v.x + v.y + v.z + v.w;
    ss += v.x * v.x + v.y * v.y + v.z * v.z + v.w * v.w;
  }
#pragma unroll
  for (int o = 32; o >= 1; o >>= 1) {
    s += __shfl_down(s, o);
    ss += __shfl_down(ss, o);
  }
  __shared__ float as_[4], ass_[4];
  const int w = threadIdx.x >> 6;
  if ((threadIdx.x & 63) == 0) { as_[w] = s; ass_[w] = ss; }
  __syncthreads();
  if (threadIdx.x == 0) {
    float st = as_[0] + as_[1] + as_[2] + as_[3];
    float sst = ass_[0] + ass_[1] + ass_[2] + ass_[3];
    float m = st * (1.f / 4096.f);
    float var = sst * (1.f / 4096.f) - m * m;
    mu[bc] = m;
    rs[bc] = rsqrtf(var + 1e-5f);
  }
}

// ---------------- cast h_w, o_w fp32 -> f16 ----------------
__global__ void __launch_bounds__(256) wcast2_k(const float* __restrict__ a,
                                                const float* __restrict__ b,
                                                f16_t* __restrict__ dst) {
  const int i = blockIdx.x * 256 + threadIdx.x;
  const int which = i >> 16;
  const int off = i & 65535;
  const float* s = which ? b : a;
  const float4 v = ((const float4*)s)[off];
  alignas(8) f16_t r[4];
  r[0] = (f16_t)v.x; r[1] = (f16_t)v.y; r[2] = (f16_t)v.z; r[3] = (f16_t)v.w;
  *(uint2*)(dst + ((size_t)which << 18) + (size_t)off * 4) = *(const uint2*)r;
}

// ---------------- Mt[j][i] = sum_c f_w[c][i]*g_w[c][j], fp32 acc -> f16 ----------------
__global__ void __launch_bounds__(256) mt_k(const float* __restrict__ fw,
                                            const float* __restrict__ gw,
                                            f16_t* __restrict__ Mh) {
  __shared__ float Fs[32][64];
  __shared__ float Gs[32][64];
  const int t = threadIdx.x;
  const int it = blockIdx.x, jt = blockIdx.y;
  float acc[16];
#pragma unroll
  for (int i = 0; i < 16; ++i) acc[i] = 0.f;
  const int jl = t >> 2, ib = (t & 3) * 16;
  const int lr = t >> 4, lc4 = (t & 15) * 4;
  for (int cc = 0; cc < 16; ++cc) {
    __syncthreads();
#pragma unroll
    for (int rep = 0; rep < 2; ++rep) {
      const int r = lr + rep * 16;
      *(float4*)&Fs[r][lc4] = *(const float4*)(fw + (size_t)(cc * 32 + r) * 512 + it * 64 + lc4);
      *(float4*)&Gs[r][lc4] = *(const float4*)(gw + (size_t)(cc * 32 + r) * 512 + jt * 64 + lc4);
    }
    __syncthreads();
#pragma unroll
    for (int c = 0; c < 32; ++c) {
      const float gv = Gs[c][jl];
#pragma unroll
      for (int ii = 0; ii < 16; ++ii) acc[ii] += gv * Fs[c][ib + ii];
    }
  }
  alignas(16) f16_t hi[16];
#pragma unroll
  for (int ii = 0; ii < 16; ++ii) hi[ii] = (f16_t)acc[ii];
  const size_t o = (size_t)(jt * 64 + jl) * 512 + it * 64 + ib;
  *(uint4*)(Mh + o) = *(const uint4*)hi;
  *(uint4*)(Mh + o + 8) = *(const uint4*)(hi + 8);
}

// ---------------- v[j] = sum_c g_w[c][j] * f_b[c] ----------------
__global__ void __launch_bounds__(256) v_k(const float* __restrict__ gw,
                                           const float* __restrict__ fb,
                                           float* __restrict__ v) {
  const int j = blockIdx.x * 256 + threadIdx.x;
  float s = 0.f;
  for (int c = 0; c < 512; ++c) s += gw[(size_t)c * 512 + j] * fb[c];
  v[j] = s;
}

// ---------------- u[b][m] = v . xn(m) ----------------
__global__ void __launch_bounds__(256) u_k(const float* __restrict__ v,
                                           const f16_t* __restrict__ xf,
                                           float* __restrict__ u) {
  const int w = threadIdx.x >> 6, lane = threadIdx.x & 63;
  const int m = blockIdx.x * 4 + w;
  const int b = blockIdx.y;
  const size_t o = ((size_t)b * 4096 + m) * 512 + lane * 8;
  const f16x8 vh = *(const f16x8*)(xf + o);
  const float4 v0 = *(const float4*)(v + lane * 8);
  const float4 v1 = *(const float4*)(v + lane * 8 + 4);
  float s = 0.f;
  const float* vp = &v0.x;
#pragma unroll
  for (int e = 0; e < 4; ++e) s += (float)vh[e] * vp[e];
  const float* vq = &v1.x;
#pragma unroll
  for (int e = 0; e < 4; ++e) s += (float)vh[4 + e] * vq[e];
#pragma unroll
  for (int o2 = 32; o2 >= 1; o2 >>= 1) s += __shfl_down(s, o2);
  if (lane == 0) u[(size_t)b * 4096 + m] = s;
}

// ---------------- normalize + transpose: x[b][c][n] -> xf (norm f16), xc (raw f16) [b][n][c] ----------------
__global__ void __launch_bounds__(256) normt_k(const float* __restrict__ x,
                                               const float* __restrict__ mu,
                                               const float* __restrict__ rs,
                                               f16_t* __restrict__ xf,
                                               f16_t* __restrict__ xc) {
  __shared__ float tile[64][65];
  const int t = threadIdx.x;
  const int nt = blockIdx.x, ct = blockIdx.y, b = blockIdx.z;
  const float* src = x + ((size_t)b * 512 + ct * 64) * 4096 + nt * 64;
  {
    const int r = t >> 4, cq = (t & 15) * 4;
#pragma unroll
    for (int it = 0; it < 4; ++it) {
      const int rr = r + it * 16;
      const float4 v = *(const float4*)(src + (size_t)rr * 4096 + cq);
      tile[rr][cq] = v.x; tile[rr][cq + 1] = v.y;
      tile[rr][cq + 2] = v.z; tile[rr][cq + 3] = v.w;
    }
  }
  __syncthreads();
  const int n = t & 63, ch = t >> 6;
  alignas(16) f16_t vf[16], vc[16];
#pragma unroll
  for (int i = 0; i < 16; ++i) {
    const int c = ch * 16 + i;
    const float v = tile[c][n];
    const int gc = b * 512 + ct * 64 + c;
    vc[i] = (f16_t)v;
    vf[i] = (f16_t)((v - mu[gc]) * rs[gc]);
  }
  const size_t o = ((size_t)b * 4096 + nt * 64 + n) * 512 + ct * 64 + ch * 16;
  *(uint4*)(xf + o) = *(const uint4*)vf;
  *(uint4*)(xf + o + 8) = *(const uint4*)(vf + 8);
  *(uint4*)(xc + o) = *(const uint4*)vc;
  *(uint4*)(xc + o + 8) = *(const uint4*)(vc + 8);
}

// ---------------- f16 GEMM (double-buffered, stage-ahead): C[m][n] = A[m][k].Bt[n][k], K=512 ----------------
template <typename OT, int BIAS, bool RESID>
__global__ void __launch_bounds__(256) gemm_k(const f16_t* __restrict__ A,
                                              const f16_t* __restrict__ Bt,
                                              OT* __restrict__ C,
                                              const float* __restrict__ biasM,
                                              const float* __restrict__ biasN,
                                              const float* __restrict__ resid,
                                              long sAb, long sBb, long sCb, int ldC) {
  __shared__ alignas(16) f16_t As[2][128 * 64];
  __shared__ alignas(16) f16_t Bs[2][128 * 64];
  const int t = threadIdx.x;
  const int lane = t & 63;
  const int w = t >> 6;
  const int wr = w >> 1, wc = w & 1;
  const int l15 = lane & 15, lg = lane >> 4;
  const int b = blockIdx.z;
  const int m0 = blockIdx.y * 128, n0 = blockIdx.x * 128;
  const f16_t* Ab = A + (size_t)sAb * b + (size_t)m0 * 512;
  const f16_t* Bb = Bt + (size_t)sBb * b + (size_t)n0 * 512;
  const int srow = t >> 3;
  const int slot = t & 7;

  auto gstage = [&](int pb_, int ks_) {
#pragma unroll
    for (int r_ = 0; r_ < 4; ++r_) {
      const int rr_ = r_ * 32 + srow;
      const size_t go_ = (size_t)rr_ * 512 + ks_ * 64 + ((slot ^ (rr_ & 7)) * 8);
      gload16(Ab + go_, (char*)As[pb_] + r_ * 4096 + w * 1024);
      gload16(Bb + go_, (char*)Bs[pb_] + r_ * 4096 + w * 1024);
    }
  };

  const f32x4 z4 = {0.f, 0.f, 0.f, 0.f};
  f32x4 acc[4][4];
#pragma unroll
  for (int i = 0; i < 4; ++i)
#pragma unroll
    for (int j = 0; j < 4; ++j) acc[i][j] = z4;

  gstage(0, 0);
  __syncthreads();
  for (int ks = 0; ks < 8; ++ks) {
    const int pb = ks & 1;
    if (ks < 7) gstage(pb ^ 1, ks + 1);
#pragma unroll
    for (int kk = 0; kk < 2; ++kk) {
      f16x8 af[4], bfr[4];
#pragma unroll
      for (int i = 0; i < 4; ++i) {
        const int ra = wr * 64 + i * 16 + l15;
        af[i] = *(const f16x8*)((const char*)As[pb] + ra * 128 + (((kk * 4 + lg) ^ (ra & 7)) * 16));
        const int rb = wc * 64 + i * 16 + l15;
        bfr[i] = *(const f16x8*)((const char*)Bs[pb] + rb * 128 + (((kk * 4 + lg) ^ (rb & 7)) * 16));
      }
#pragma unroll
      for (int i = 0; i < 4; ++i)
#pragma unroll
        for (int j = 0; j < 4; ++j)
          acc[i][j] = __builtin_amdgcn_mfma_f32_16x16x32_f16(af[i], bfr[j], acc[i][j], 0, 0, 0);
    }
    __syncthreads();
  }
  OT* Cb = C + (size_t)sCb * b;
#pragma unroll
  for (int i = 0; i < 4; ++i) {
#pragma unroll
    for (int j = 0; j < 4; ++j) {
      const int n = n0 + wc * 64 + j * 16 + l15;
      float bn = 0.f;
      if (BIAS == 2) bn = biasN[n];
#pragma unroll
      for (int r = 0; r < 4; ++r) {
        const int m = m0 + wr * 64 + i * 16 + lg * 4 + r;
        float v = acc[i][j][r] + bn;
        if (BIAS == 1) v += biasM[m];
        if (RESID) v += resid[(size_t)sCb * b + (size_t)m * ldC + n];
        Cb[(size_t)m * ldC + n] = (OT)v;
      }
    }
  }
}

// ---------------- flash attention v6: 4 waves, q=32, 2 anti-phase blocks/CU ----------------
// Waves: wq=w&1 (16 q), wk=w>>1 (32 keys). K=xf[b][k][c] 64KB single-buffer LDS.
// Per tile: [u,vpre0 issue] B1(K ready) QK | u-add,max,redm | vpre1 issue | B2 | stage(t+1)
//           softmax,P,reds | B3 | l,rescale,PV(kk0=vpre0, kk1=vpre1).
// vmcnt ledger: B1 waits vmcnt(10) (retires stage16, keeps u2+vpre0_8); u-add waits (8);
// vpre0 waits (24) (keeps vpre1_8+stage16); vpre1 waits (16) (keeps stage16). Never drains stage.
__global__ void __launch_bounds__(256, 1) flash_k(const f16_t* __restrict__ Z,
                                                  const f16_t* __restrict__ X,
                                                  const float* __restrict__ u,
                                                  const f16_t* __restrict__ Hv,
                                                  f16_t* __restrict__ Oat_t) {
  __shared__ alignas(16) f16_t K[64 * 512];  // 64KB, 1024B rows, slot-swizzled via source
  __shared__ alignas(16) f16_t P[32 * 72];   // 4.5KB, 144B rows
  __shared__ float redm[2][2][16];
  __shared__ float reds[2][2][16];
  __shared__ float alds[32];
  __shared__ float llds[32];

  const int t = threadIdx.x;
  const int lane = t & 63;
  const int w = t >> 6;  // 0..3
  const int wq = w & 1, wk = w >> 1;
  const int l15 = lane & 15, lg = lane >> 4;
  const int bid = blockIdx.x;  // 512 blocks
  const int xcd = bid & 7;
  const int b = xcd >> 1;
  const int q0 = ((xcd & 1) * 64 + (bid >> 3)) * 32;

  const f16_t* Kb = X + (size_t)b * 4096 * 512;
  const f16_t* Vb = Hv + (size_t)b * 512 * 4096;
  const float* ub = u + (size_t)b * 4096;

  // stage 64 keys x 512 c (64KB): 16 gload16/thread; wave w covers rows r*4+w.
  auto stagek = [&](int kt_) {
    const int k0_ = kt_ * 64;
#pragma unroll
    for (int r_ = 0; r_ < 16; ++r_) {
      const int row_ = r_ * 4 + w;
      gload16(Kb + (size_t)(k0_ + row_) * 512 + ((lane ^ (row_ & 7)) * 8),
              (char*)K + row_ * 1024);
    }
  };

  // Q frags: q = q0 + 16*wq + l15, c window cw*32 + lg*8
  f16x8 qf[16];
  {
    const size_t qo = ((size_t)b * 4096 + q0 + 16 * wq + l15) * 512 + lg * 8;
#pragma unroll
    for (int cw = 0; cw < 16; ++cw) qf[cw] = *(const f16x8*)(Z + qo + cw * 32);
  }
  stagek(0);  // prologue

  const f32x4 z4 = {0.f, 0.f, 0.f, 0.f};
  f32x4 oacc[8][2];
#pragma unroll
  for (int i = 0; i < 8; ++i) { oacc[i][0] = z4; oacc[i][1] = z4; }
  float m_run = -3.0e38f, l_run = 0.f;
  const int qrow = 16 * wq + l15;
  const int cbase = 128 * w + l15;

  for (int kt = 0; kt < 64; ++kt) {
    const int k0 = kt * 64;
    // ---- issue u + vpre0 (stage(kt) outstanding: 16) ----
    const float4 u0 = *(const float4*)(ub + k0 + 32 * wk + 4 * lg);
    const float4 u1 = *(const float4*)(ub + k0 + 32 * wk + 16 + 4 * lg);
    f16x8 vpre0[8];
#pragma unroll
    for (int ct = 0; ct < 8; ++ct)
      vpre0[ct] = *(const f16x8*)(Vb + (size_t)(cbase + 16 * ct) * 4096 + k0 + lg * 8);
    // ---- B1: K(kt) ready (retire stage16, keep u2+vpre0_8) ----
    WAITV10(); WAITL(); SB(); SCHED0();
    // ---- QK(kt): 32 ds_read + 32 MFMA per wave ----
    f32x4 sacc[2] = {z4, z4};
    __builtin_amdgcn_s_setprio(1);
#pragma unroll
    for (int cwl = 0; cwl < 16; ++cwl) {
      const f16x8 qfv = qf[cwl];
#pragma unroll
      for (int mf = 0; mf < 2; ++mf) {
        const int key = 32 * wk + 16 * mf + l15;
        const int slot = (cwl * 4 + lg) ^ (key & 7);
        const f16x8 kf = *(const f16x8*)((const char*)K + key * 1024 + slot * 16);
        sacc[mf] = __builtin_amdgcn_mfma_f32_16x16x32_f16(kf, qfv, sacc[mf], 0, 0, 0);
      }
    }
    __builtin_amdgcn_s_setprio(0);
    // ---- u add + local max ----
    float pm = -3.0e38f;
    {
      const float* up0 = &u0.x;
      const float* up1 = &u1.x;
#pragma unroll
      for (int j = 0; j < 4; ++j) {
        sacc[0][j] += up0[j];
        sacc[1][j] += up1[j];
        pm = fmaxf(pm, fmaxf(sacc[0][j], sacc[1][j]));
      }
    }
    pm = fmaxf(pm, __shfl_xor(pm, 16));
    pm = fmaxf(pm, __shfl_xor(pm, 32));
    if (lane < 16) redm[wq][wk][lane] = pm;
    // ---- issue vpre1 BEFORE stage so consuming it never drains the stage ----
    f16x8 vpre1[8];
#pragma unroll
    for (int ct = 0; ct < 8; ++ct)
      vpre1[ct] = *(const f16x8*)(Vb + (size_t)(cbase + 16 * ct) * 4096 + k0 + 32 + lg * 8);
    // ---- B2: redm visible; all K(kt) ds_reads done -> safe to restage ----
    WAITL(); SB(); SCHED0();
    stagek((kt + 1) & 63);
    // ---- softmax: defer-max (THR=8), P write, reds/alds ----
    const float m_tile = fmaxf(pm, redm[wq][wk ^ 1][l15]);
    float alpha;
    if (m_tile > m_run + 8.f) {
      alpha = exp2f((m_run - m_tile) * LOG2E);
      m_run = m_tile;
    } else {
      alpha = 1.f;
    }
    float ps = 0.f;
    {
      alignas(8) f16_t pk[4];
#pragma unroll
      for (int mf = 0; mf < 2; ++mf) {
#pragma unroll
        for (int j = 0; j < 4; ++j) {
          const float p = exp2f((sacc[mf][j] - m_run) * LOG2E);
          ps += p;
          pk[j] = (f16_t)p;
        }
        *(uint2*)((char*)P + qrow * 144 + 64 * wk + 32 * mf + 8 * lg) = *(const uint2*)pk;
      }
    }
    ps += __shfl_xor(ps, 16);
    ps += __shfl_xor(ps, 32);
    if (lane < 16) {
      reds[wq][wk][lane] = ps;
      if (wk == 0) alds[16 * wq + lane] = alpha;
    }
    // ---- B3: P/reds/alds visible ----
    WAITL(); SB(); SCHED0();
    l_run = l_run * alpha + reds[wq][0][l15] + reds[wq][1][l15];
    // ---- rescale (skippable) + PV(kt) ----
    float aq[2];
    aq[0] = alds[l15];
    aq[1] = alds[16 + l15];
    const bool need = (aq[0] != 1.f) || (aq[1] != 1.f);
    if (__any(need)) {
#pragma unroll
      for (int ct = 0; ct < 8; ++ct) {
        oacc[ct][0] *= aq[0];
        oacc[ct][1] *= aq[1];
      }
    }
    __builtin_amdgcn_s_setprio(1);
#pragma unroll
    for (int kk = 0; kk < 2; ++kk) {
      f16x8 bp[2];
#pragma unroll
      for (int qt = 0; qt < 2; ++qt)
        bp[qt] = *(const f16x8*)((const char*)P + (16 * qt + l15) * 144 + kk * 64 + lg * 16);
#pragma unroll
      for (int ct = 0; ct < 8; ++ct) {
        const f16x8 vf = kk ? vpre1[ct] : vpre0[ct];
#pragma unroll
        for (int qt = 0; qt < 2; ++qt)
          oacc[ct][qt] = __builtin_amdgcn_mfma_f32_16x16x32_f16(vf, bp[qt], oacc[ct][qt], 0, 0, 0);
      }
    }
    __builtin_amdgcn_s_setprio(0);
  }
  // ---- epilogue: divide by l, store transposed [q][c] ----
  if (wk == 0 && lane < 16) llds[16 * wq + lane] = l_run;
  __syncthreads();
  float inv[2];
  inv[0] = 1.f / llds[l15];
  inv[1] = 1.f / llds[16 + l15];
#pragma unroll
  for (int ct = 0; ct < 8; ++ct)
#pragma unroll
    for (int qt = 0; qt < 2; ++qt) {
      alignas(8) f16_t o4[4];
#pragma unroll
      for (int j = 0; j < 4; ++j) o4[j] = (f16_t)(oacc[ct][qt][j] * inv[qt]);
      *(uint2*)(Oat_t + ((size_t)b * 4096 + q0 + 16 * qt + l15) * 512 + 128 * w + 16 * ct + 4 * lg) =
          *(const uint2*)o4;
    }
}

// ---------------- host launch ----------------
extern "C" void kernel_launch(void* const* d_in, const int* in_sizes, int n_in,
                              void* d_out, int out_size, void* d_ws, size_t ws_size,
                              hipStream_t stream) {
  const float* x = (const float*)d_in[0];
  const float* fw = (const float*)d_in[1];
  const float* fb = (const float*)d_in[2];
  const float* gw = (const float*)d_in[3];
  const float* gb = (const float*)d_in[4];
  const float* hw = (const float*)d_in[5];
  const float* hb = (const float*)d_in[6];
  const float* ow = (const float*)d_in[7];
  const float* ob = (const float*)d_in[8];
  float* out = (float*)d_out;
  (void)gb;

  const size_t BIG = (size_t)4 * 4096 * 512 * sizeof(f16_t);  // 16.78MB
  char* p = (char*)d_ws;
  float* mu = (float*)p; p += 2048 * sizeof(float);
  float* rs = (float*)p; p += 2048 * sizeof(float);
  float* vv = (float*)p; p += 512 * sizeof(float);
  float* uu = (float*)p; p += (size_t)4 * 4096 * sizeof(float);
  f16_t* w2 = (f16_t*)p; p += (size_t)2 * 512 * 512 * sizeof(f16_t);
  f16_t* Mh = (f16_t*)p; p += (size_t)512 * 512 * sizeof(f16_t);
  f16_t* xf = (f16_t*)p; p += BIG;
  f16_t* xc = (f16_t*)p; p += BIG;
  f16_t* Zf = (f16_t*)p; p += BIG;
  f16_t* Hv = (f16_t*)p; p += BIG;  // total ~70MB
  f16_t* Oat_t = xc;                // alias: xc dead after Hv gemm

  f16_t* whb = w2;
  f16_t* wob = w2 + 262144;

  const long sD = (long)4096 * 512;

  stats_k<<<2048, 256, 0, stream>>>(x, mu, rs);
  wcast2_k<<<512, 256, 0, stream>>>(hw, ow, w2);
  mt_k<<<dim3(8, 8), 256, 0, stream>>>(fw, gw, Mh);
  v_k<<<2, 256, 0, stream>>>(gw, fb, vv);
  normt_k<<<dim3(64, 8, 4), 256, 0, stream>>>(x, mu, rs, xf, xc);
  u_k<<<dim3(1024, 4), 256, 0, stream>>>(vv, xf, uu);
  // Z[b][n][j] = sum_i xf[n][i] * Mh[j][i]
  gemm_k<f16_t, 0, false><<<dim3(4, 32, 4), 256, 0, stream>>>(
      xf, Mh, Zf, nullptr, nullptr, nullptr, sD, 0, sD, 512);
  // Hv[b][c][n] = h_w . xc  (+h_b over c)
  gemm_k<f16_t, 1, false><<<dim3(32, 4, 4), 256, 0, stream>>>(
      whb, xc, Hv, hb, nullptr, nullptr, 0, sD, sD, 4096);
  // attention (512 blocks x 256 threads, 2 blocks/CU) -> Oat_t[b][q][c]
  flash_k<<<512, 256, 0, stream>>>(Zf, xf, uu, Hv, Oat_t);
  // out[b][o][n] = o_w . Oat_t^T (+o_b over o) + residual, fp32
  gemm_k<float, 1, true><<<dim3(32, 4, 4), 256, 0, stream>>>(
      wob, Oat_t, out, ob, nullptr, x, 0, sD, sD, 4096);

  (void)in_sizes; (void)n_in; (void)out_size; (void)ws_size;
}

// Round 10
// 412.316 us; speedup vs baseline: 1.4438x; 1.4438x over previous
//
#include <hip/hip_runtime.h>

// Content_SA: instance-norm -> f/g/h 1x1 convs -> attention(QK^T softmax, PV) -> o conv + residual.
// B=4, C=512, H=W=64 (N=4096).
// Algebra: energy[n,m] = xn(n)^T M xn(m) + u[m] (+ query-const, cancels in softmax), M = f_w^T g_w (fp32).
// Precision: M,Z,xn,V all f16 (single rounding from fp32-grade values); softmax fp32.
// Flash v9: q=64/block, 8 waves (wq4 x wk2), K-tile k=128 SINGLE-buffer (128KB), 32 tiles,
// 3 barriers/tile (vs R8's 6 per 128k). Stage split in halves, interleaved with PV so the
// ordered vmcnt ledger never drains an in-flight stage (R7 lesson). V regs capped at 32.

typedef __bf16 bf16_t;
typedef _Float16 f16_t;
typedef _Float16 f16x8 __attribute__((ext_vector_type(8)));
typedef float f32x4 __attribute__((ext_vector_type(4)));

#define LOG2E 1.44269504088896340736f

__device__ __forceinline__ void gload16(const void* g, void* l) {
  __builtin_amdgcn_global_load_lds(
      (const __attribute__((address_space(1))) void*)g,
      (__attribute__((address_space(3))) void*)l, 16, 0, 0);
}

#define WAITV4() asm volatile("s_waitcnt vmcnt(4)" ::: "memory")
#define WAITL() asm volatile("s_waitcnt lgkmcnt(0)" ::: "memory")
#define SB() __builtin_amdgcn_s_barrier()
#define SCHED0() __builtin_amdgcn_sched_barrier(0)

// ---------------- instance-norm statistics ----------------
__global__ void __launch_bounds__(256) stats_k(const float* __restrict__ x,
                                               float* __restrict__ mu,
                                               float* __restrict__ rs) {
  const int bc = blockIdx.x;
  const float4* row = (const float4*)(x + (size_t)bc * 4096);
  float s = 0.f, ss = 0.f;
  for (int i = threadIdx.x; i < 1024; i += 256) {
    float4 v = row[i];
    s += v.x + v.y + v.z + v.w;
    ss += v.x * v.x + v.y * v.y + v.z * v.z + v.w * v.w;
  }
#pragma unroll
  for (int o = 32; o >= 1; o >>= 1) {
    s += __shfl_down(s, o);
    ss += __shfl_down(ss, o);
  }
  __shared__ float as_[4], ass_[4];
  const int w = threadIdx.x >> 6;
  if ((threadIdx.x & 63) == 0) { as_[w] = s; ass_[w] = ss; }
  __syncthreads();
  if (threadIdx.x == 0) {
    float st = as_[0] + as_[1] + as_[2] + as_[3];
    float sst = ass_[0] + ass_[1] + ass_[2] + ass_[3];
    float m = st * (1.f / 4096.f);
    float var = sst * (1.f / 4096.f) - m * m;
    mu[bc] = m;
    rs[bc] = rsqrtf(var + 1e-5f);
  }
}

// ---------------- cast h_w, o_w fp32 -> f16 ----------------
__global__ void __launch_bounds__(256) wcast2_k(const float* __restrict__ a,
                                                const float* __restrict__ b,
                                                f16_t* __restrict__ dst) {
  const int i = blockIdx.x * 256 + threadIdx.x;
  const int which = i >> 16;
  const int off = i & 65535;
  const float* s = which ? b : a;
  const float4 v = ((const float4*)s)[off];
  alignas(8) f16_t r[4];
  r[0] = (f16_t)v.x; r[1] = (f16_t)v.y; r[2] = (f16_t)v.z; r[3] = (f16_t)v.w;
  *(uint2*)(dst + ((size_t)which << 18) + (size_t)off * 4) = *(const uint2*)r;
}

// ---------------- Mt[j][i] = sum_c f_w[c][i]*g_w[c][j], fp32 acc -> f16 ----------------
__global__ void __launch_bounds__(256) mt_k(const float* __restrict__ fw,
                                            const float* __restrict__ gw,
                                            f16_t* __restrict__ Mh) {
  __shared__ float Fs[32][64];
  __shared__ float Gs[32][64];
  const int t = threadIdx.x;
  const int it = blockIdx.x, jt = blockIdx.y;
  float acc[16];
#pragma unroll
  for (int i = 0; i < 16; ++i) acc[i] = 0.f;
  const int jl = t >> 2, ib = (t & 3) * 16;
  const int lr = t >> 4, lc4 = (t & 15) * 4;
  for (int cc = 0; cc < 16; ++cc) {
    __syncthreads();
#pragma unroll
    for (int rep = 0; rep < 2; ++rep) {
      const int r = lr + rep * 16;
      *(float4*)&Fs[r][lc4] = *(const float4*)(fw + (size_t)(cc * 32 + r) * 512 + it * 64 + lc4);
      *(float4*)&Gs[r][lc4] = *(const float4*)(gw + (size_t)(cc * 32 + r) * 512 + jt * 64 + lc4);
    }
    __syncthreads();
#pragma unroll
    for (int c = 0; c < 32; ++c) {
      const float gv = Gs[c][jl];
#pragma unroll
      for (int ii = 0; ii < 16; ++ii) acc[ii] += gv * Fs[c][ib + ii];
    }
  }
  alignas(16) f16_t hi[16];
#pragma unroll
  for (int ii = 0; ii < 16; ++ii) hi[ii] = (f16_t)acc[ii];
  const size_t o = (size_t)(jt * 64 + jl) * 512 + it * 64 + ib;
  *(uint4*)(Mh + o) = *(const uint4*)hi;
  *(uint4*)(Mh + o + 8) = *(const uint4*)(hi + 8);
}

// ---------------- v[j] = sum_c g_w[c][j] * f_b[c] ----------------
__global__ void __launch_bounds__(256) v_k(const float* __restrict__ gw,
                                           const float* __restrict__ fb,
                                           float* __restrict__ v) {
  const int j = blockIdx.x * 256 + threadIdx.x;
  float s = 0.f;
  for (int c = 0; c < 512; ++c) s += gw[(size_t)c * 512 + j] * fb[c];
  v[j] = s;
}

// ---------------- u[b][m] = v . xn(m) ----------------
__global__ void __launch_bounds__(256) u_k(const float* __restrict__ v,
                                           const f16_t* __restrict__ xf,
                                           float* __restrict__ u) {
  const int w = threadIdx.x >> 6, lane = threadIdx.x & 63;
  const int m = blockIdx.x * 4 + w;
  const int b = blockIdx.y;
  const size_t o = ((size_t)b * 4096 + m) * 512 + lane * 8;
  const f16x8 vh = *(const f16x8*)(xf + o);
  const float4 v0 = *(const float4*)(v + lane * 8);
  const float4 v1 = *(const float4*)(v + lane * 8 + 4);
  float s = 0.f;
  const float* vp = &v0.x;
#pragma unroll
  for (int e = 0; e < 4; ++e) s += (float)vh[e] * vp[e];
  const float* vq = &v1.x;
#pragma unroll
  for (int e = 0; e < 4; ++e) s += (float)vh[4 + e] * vq[e];
#pragma unroll
  for (int o2 = 32; o2 >= 1; o2 >>= 1) s += __shfl_down(s, o2);
  if (lane == 0) u[(size_t)b * 4096 + m] = s;
}

// ---------------- normalize + transpose: x[b][c][n] -> xf (norm f16), xc (raw f16) [b][n][c] ----------------
__global__ void __launch_bounds__(256) normt_k(const float* __restrict__ x,
                                               const float* __restrict__ mu,
                                               const float* __restrict__ rs,
                                               f16_t* __restrict__ xf,
                                               f16_t* __restrict__ xc) {
  __shared__ float tile[64][65];
  const int t = threadIdx.x;
  const int nt = blockIdx.x, ct = blockIdx.y, b = blockIdx.z;
  const float* src = x + ((size_t)b * 512 + ct * 64) * 4096 + nt * 64;
  {
    const int r = t >> 4, cq = (t & 15) * 4;
#pragma unroll
    for (int it = 0; it < 4; ++it) {
      const int rr = r + it * 16;
      const float4 v = *(const float4*)(src + (size_t)rr * 4096 + cq);
      tile[rr][cq] = v.x; tile[rr][cq + 1] = v.y;
      tile[rr][cq + 2] = v.z; tile[rr][cq + 3] = v.w;
    }
  }
  __syncthreads();
  const int n = t & 63, ch = t >> 6;
  alignas(16) f16_t vf[16], vc[16];
#pragma unroll
  for (int i = 0; i < 16; ++i) {
    const int c = ch * 16 + i;
    const float v = tile[c][n];
    const int gc = b * 512 + ct * 64 + c;
    vc[i] = (f16_t)v;
    vf[i] = (f16_t)((v - mu[gc]) * rs[gc]);
  }
  const size_t o = ((size_t)b * 4096 + nt * 64 + n) * 512 + ct * 64 + ch * 16;
  *(uint4*)(xf + o) = *(const uint4*)vf;
  *(uint4*)(xf + o + 8) = *(const uint4*)(vf + 8);
  *(uint4*)(xc + o) = *(const uint4*)vc;
  *(uint4*)(xc + o + 8) = *(const uint4*)(vc + 8);
}

// ---------------- f16 GEMM (double-buffered, stage-ahead): C[m][n] = A[m][k].Bt[n][k], K=512 ----------------
template <typename OT, int BIAS, bool RESID>
__global__ void __launch_bounds__(256) gemm_k(const f16_t* __restrict__ A,
                                              const f16_t* __restrict__ Bt,
                                              OT* __restrict__ C,
                                              const float* __restrict__ biasM,
                                              const float* __restrict__ biasN,
                                              const float* __restrict__ resid,
                                              long sAb, long sBb, long sCb, int ldC) {
  __shared__ alignas(16) f16_t As[2][128 * 64];
  __shared__ alignas(16) f16_t Bs[2][128 * 64];
  const int t = threadIdx.x;
  const int lane = t & 63;
  const int w = t >> 6;
  const int wr = w >> 1, wc = w & 1;
  const int l15 = lane & 15, lg = lane >> 4;
  const int b = blockIdx.z;
  const int m0 = blockIdx.y * 128, n0 = blockIdx.x * 128;
  const f16_t* Ab = A + (size_t)sAb * b + (size_t)m0 * 512;
  const f16_t* Bb = Bt + (size_t)sBb * b + (size_t)n0 * 512;
  const int srow = t >> 3;
  const int slot = t & 7;

  auto gstage = [&](int pb_, int ks_) {
#pragma unroll
    for (int r_ = 0; r_ < 4; ++r_) {
      const int rr_ = r_ * 32 + srow;
      const size_t go_ = (size_t)rr_ * 512 + ks_ * 64 + ((slot ^ (rr_ & 7)) * 8);
      gload16(Ab + go_, (char*)As[pb_] + r_ * 4096 + w * 1024);
      gload16(Bb + go_, (char*)Bs[pb_] + r_ * 4096 + w * 1024);
    }
  };

  const f32x4 z4 = {0.f, 0.f, 0.f, 0.f};
  f32x4 acc[4][4];
#pragma unroll
  for (int i = 0; i < 4; ++i)
#pragma unroll
    for (int j = 0; j < 4; ++j) acc[i][j] = z4;

  gstage(0, 0);
  __syncthreads();
  for (int ks = 0; ks < 8; ++ks) {
    const int pb = ks & 1;
    if (ks < 7) gstage(pb ^ 1, ks + 1);
#pragma unroll
    for (int kk = 0; kk < 2; ++kk) {
      f16x8 af[4], bfr[4];
#pragma unroll
      for (int i = 0; i < 4; ++i) {
        const int ra = wr * 64 + i * 16 + l15;
        af[i] = *(const f16x8*)((const char*)As[pb] + ra * 128 + (((kk * 4 + lg) ^ (ra & 7)) * 16));
        const int rb = wc * 64 + i * 16 + l15;
        bfr[i] = *(const f16x8*)((const char*)Bs[pb] + rb * 128 + (((kk * 4 + lg) ^ (rb & 7)) * 16));
      }
#pragma unroll
      for (int i = 0; i < 4; ++i)
#pragma unroll
        for (int j = 0; j < 4; ++j)
          acc[i][j] = __builtin_amdgcn_mfma_f32_16x16x32_f16(af[i], bfr[j], acc[i][j], 0, 0, 0);
    }
    __syncthreads();
  }
  OT* Cb = C + (size_t)sCb * b;
#pragma unroll
  for (int i = 0; i < 4; ++i) {
#pragma unroll
    for (int j = 0; j < 4; ++j) {
      const int n = n0 + wc * 64 + j * 16 + l15;
      float bn = 0.f;
      if (BIAS == 2) bn = biasN[n];
#pragma unroll
      for (int r = 0; r < 4; ++r) {
        const int m = m0 + wr * 64 + i * 16 + lg * 4 + r;
        float v = acc[i][j][r] + bn;
        if (BIAS == 1) v += biasM[m];
        if (RESID) v += resid[(size_t)sCb * b + (size_t)m * ldC + n];
        Cb[(size_t)m * ldC + n] = (OT)v;
      }
    }
  }
}

// ---------------- flash attention v9: k-tile=128 single-buffer, 3 barriers/tile ----------------
// Q=Z[b][q][c] f16 in regs; K=xf[b][k][c] 128KB LDS tile; V=Hv[b][c][k]; out Oat_t[b][q][c].
// 8 waves: wq=w&3 (16 q), wk=w>>2 (64 keys each). 32 tiles.
// Per-tile VMEM ledger (per wave):      outstanding after
//   issue u(4)                          stage_h1(8)+u(4)=12
//   B1: vmcnt(4) retires stage_h1       u(4)
//   QK ; u-consume (vmcnt 0)            0
//   B2 ; issue vA(8) ; stage_h0(8)      16
//   softmax ; B3
//   PV kk01: vA waits vmcnt(8)          stage_h0(8)
//   issue vB(8) ; stage_h1(8)           24
//   PV kk23: vB waits vmcnt(8) (retires stage_h0 after ~full flight, keeps stage_h1)
__global__ void __launch_bounds__(512, 1) flash_k(const f16_t* __restrict__ Z,
                                                  const f16_t* __restrict__ X,
                                                  const float* __restrict__ u,
                                                  const f16_t* __restrict__ Hv,
                                                  f16_t* __restrict__ Oat_t) {
  __shared__ alignas(16) f16_t K[128 * 512];  // 128KB, 1024B rows, slot-swizzled via source
  __shared__ alignas(16) f16_t P[64 * 136];   // 17KB, 272B rows (2-way alias only)
  __shared__ float redm[4][2][16];
  __shared__ float reds[4][2][16];
  __shared__ float alds[64];
  __shared__ float llds[64];

  const int t = threadIdx.x;
  const int lane = t & 63;
  const int w = t >> 6;
  const int wq = w & 3, wk = w >> 2;
  const int l15 = lane & 15, lg = lane >> 4;
  const int bid = blockIdx.x;
  const int xcd = bid & 7;
  const int b = xcd >> 1;
  const int q0 = ((xcd & 1) * 32 + (bid >> 3)) * 64;

  const f16_t* Kb = X + (size_t)b * 4096 * 512;
  const f16_t* Vb = Hv + (size_t)b * 512 * 4096;
  const float* ub = u + (size_t)b * 4096;

  // stage one 64-row half of the 128x512 K tile: 8 gload16/thread.
  auto stageh = [&](int kt_, int half_) {
    const int k0_ = kt_ * 128 + half_ * 64;
#pragma unroll
    for (int r_ = 0; r_ < 8; ++r_) {
      const int row_ = half_ * 64 + r_ * 8 + w;
      gload16(Kb + (size_t)(k0_ + r_ * 8 + w) * 512 + ((lane ^ (row_ & 7)) * 8),
              (char*)K + row_ * 1024);
    }
  };

  // Q frags: q = q0 + 16*wq + l15, c window cw*32 + lg*8
  f16x8 qf[16];
  {
    const size_t qo = ((size_t)b * 4096 + q0 + 16 * wq + l15) * 512 + lg * 8;
#pragma unroll
    for (int cw = 0; cw < 16; ++cw) qf[cw] = *(const f16x8*)(Z + qo + cw * 32);
  }
  stageh(0, 0);
  stageh(0, 1);  // prologue: 16 loads in flight

  const f32x4 z4 = {0.f, 0.f, 0.f, 0.f};
  f32x4 oacc[4][4];
#pragma unroll
  for (int i = 0; i < 4; ++i)
#pragma unroll
    for (int j = 0; j < 4; ++j) oacc[i][j] = z4;
  float m_run = -3.0e38f, l_run = 0.f;
  const int qrow = 16 * wq + l15;

  for (int kt = 0; kt < 32; ++kt) {
    const int k0 = kt * 128;
    const int ktn = (kt + 1) & 31;
    // ---- issue u (4 x float4; this wave's k-range = 64*wk) ----
    float4 uq[4];
#pragma unroll
    for (int mf = 0; mf < 4; ++mf)
      uq[mf] = *(const float4*)(ub + k0 + 64 * wk + 16 * mf + 4 * lg);
    // ---- B1: K tile ready (retire trailing stage half, keep u) ----
    WAITV4(); WAITL(); SB(); SCHED0();
    // ---- QK: 64 ds_read_b128 + 64 MFMA per wave ----
    f32x4 sacc[4] = {z4, z4, z4, z4};
    __builtin_amdgcn_s_setprio(1);
#pragma unroll
    for (int cwl = 0; cwl < 16; ++cwl) {
      const f16x8 qfv = qf[cwl];
#pragma unroll
      for (int mf = 0; mf < 4; ++mf) {
        const int key = 64 * wk + 16 * mf + l15;
        const int slot = (cwl * 4 + lg) ^ (key & 7);
        const f16x8 kf = *(const f16x8*)((const char*)K + key * 1024 + slot * 16);
        sacc[mf] = __builtin_amdgcn_mfma_f32_16x16x32_f16(kf, qfv, sacc[mf], 0, 0, 0);
      }
    }
    __builtin_amdgcn_s_setprio(0);
    // ---- u add + local max over 16 vals ----
    float pm = -3.0e38f;
#pragma unroll
    for (int mf = 0; mf < 4; ++mf) {
      const float* up = &uq[mf].x;
#pragma unroll
      for (int j = 0; j < 4; ++j) {
        sacc[mf][j] += up[j];
        pm = fmaxf(pm, sacc[mf][j]);
      }
    }
    pm = fmaxf(pm, __shfl_xor(pm, 16));
    pm = fmaxf(pm, __shfl_xor(pm, 32));
    if (lane < 16) redm[wq][wk][lane] = pm;
    WAITL();
    // ---- B2: redm visible; all K reads done -> safe to restage ----
    SB(); SCHED0();
    // ---- issue V kk0/kk1 (8) THEN stage half0 (8): consumers keep stage flying ----
    f16x8 vA[2][4];
#pragma unroll
    for (int kk = 0; kk < 2; ++kk)
#pragma unroll
      for (int ct = 0; ct < 4; ++ct)
        vA[kk][ct] = *(const f16x8*)(Vb + (size_t)(64 * w + 16 * ct + l15) * 4096 + k0 + 32 * kk + 8 * lg);
    stageh(ktn, 0);
    // ---- softmax: defer-max (THR=8), P write, reds/alds ----
    const float m_tile = fmaxf(pm, redm[wq][wk ^ 1][l15]);
    float alpha;
    if (m_tile > m_run + 8.f) {
      alpha = exp2f((m_run - m_tile) * LOG2E);
      m_run = m_tile;
    } else {
      alpha = 1.f;
    }
    float ps = 0.f;
    {
      alignas(8) f16_t pk[4];
#pragma unroll
      for (int mf = 0; mf < 4; ++mf) {
#pragma unroll
        for (int j = 0; j < 4; ++j) {
          const float p = exp2f((sacc[mf][j] - m_run) * LOG2E);
          ps += p;
          pk[j] = (f16_t)p;
        }
        *(uint2*)((char*)P + qrow * 272 + 128 * wk + 32 * mf + 8 * lg) = *(const uint2*)pk;
      }
    }
    ps += __shfl_xor(ps, 16);
    ps += __shfl_xor(ps, 32);
    if (lane < 16) {
      reds[wq][wk][lane] = ps;
      if (wk == 0) alds[16 * wq + lane] = alpha;
    }
    WAITL();
    // ---- B3: P/reds/alds visible ----
    SB(); SCHED0();
    l_run = l_run * alpha + reds[wq][0][l15] + reds[wq][1][l15];
    float aq[4];
#pragma unroll
    for (int qt = 0; qt < 4; ++qt) aq[qt] = alds[16 * qt + l15];
    const bool need = (aq[0] != 1.f) || (aq[1] != 1.f) || (aq[2] != 1.f) || (aq[3] != 1.f);
    if (__any(need)) {
#pragma unroll
      for (int ct = 0; ct < 4; ++ct)
#pragma unroll
        for (int qt = 0; qt < 4; ++qt) oacc[ct][qt] *= aq[qt];
    }
    // ---- PV kk0/kk1 (vA waits vmcnt(8): stage half0 keeps flying) ----
    __builtin_amdgcn_s_setprio(1);
#pragma unroll
    for (int kk = 0; kk < 2; ++kk) {
      f16x8 bp[4];
#pragma unroll
      for (int qt = 0; qt < 4; ++qt)
        bp[qt] = *(const f16x8*)((const char*)P + (16 * qt + l15) * 272 + kk * 64 + 16 * lg);
#pragma unroll
      for (int ct = 0; ct < 4; ++ct)
#pragma unroll
        for (int qt = 0; qt < 4; ++qt)
          oacc[ct][qt] =
              __builtin_amdgcn_mfma_f32_16x16x32_f16(vA[kk][ct], bp[qt], oacc[ct][qt], 0, 0, 0);
    }
    __builtin_amdgcn_s_setprio(0);
    // ---- issue V kk2/kk3 (8) THEN stage half1 (8); PV kk2/kk3 ----
    f16x8 vB[2][4];
#pragma unroll
    for (int kk = 0; kk < 2; ++kk)
#pragma unroll
      for (int ct = 0; ct < 4; ++ct)
        vB[kk][ct] = *(const f16x8*)(Vb + (size_t)(64 * w + 16 * ct + l15) * 4096 + k0 + 64 + 32 * kk + 8 * lg);
    stageh(ktn, 1);
    __builtin_amdgcn_s_setprio(1);
#pragma unroll
    for (int kk = 0; kk < 2; ++kk) {
      f16x8 bp[4];
#pragma unroll
      for (int qt = 0; qt < 4; ++qt)
        bp[qt] = *(const f16x8*)((const char*)P + (16 * qt + l15) * 272 + (kk + 2) * 64 + 16 * lg);
#pragma unroll
      for (int ct = 0; ct < 4; ++ct)
#pragma unroll
        for (int qt = 0; qt < 4; ++qt)
          oacc[ct][qt] =
              __builtin_amdgcn_mfma_f32_16x16x32_f16(vB[kk][ct], bp[qt], oacc[ct][qt], 0, 0, 0);
    }
    __builtin_amdgcn_s_setprio(0);
  }
  // ---- epilogue: divide by l, store transposed [q][c] ----
  if (wk == 0 && lane < 16) llds[16 * wq + lane] = l_run;
  __syncthreads();
  float inv[4];
#pragma unroll
  for (int qt = 0; qt < 4; ++qt) inv[qt] = 1.f / llds[16 * qt + l15];
#pragma unroll
  for (int ct = 0; ct < 4; ++ct)
#pragma unroll
    for (int qt = 0; qt < 4; ++qt) {
      alignas(8) f16_t o4[4];
#pragma unroll
      for (int j = 0; j < 4; ++j) o4[j] = (f16_t)(oacc[ct][qt][j] * inv[qt]);
      *(uint2*)(Oat_t + ((size_t)b * 4096 + q0 + 16 * qt + l15) * 512 + 64 * w + 16 * ct + 4 * lg) =
          *(const uint2*)o4;
    }
}

// ---------------- host launch ----------------
extern "C" void kernel_launch(void* const* d_in, const int* in_sizes, int n_in,
                              void* d_out, int out_size, void* d_ws, size_t ws_size,
                              hipStream_t stream) {
  const float* x = (const float*)d_in[0];
  const float* fw = (const float*)d_in[1];
  const float* fb = (const float*)d_in[2];
  const float* gw = (const float*)d_in[3];
  const float* gb = (const float*)d_in[4];
  const float* hw = (const float*)d_in[5];
  const float* hb = (const float*)d_in[6];
  const float* ow = (const float*)d_in[7];
  const float* ob = (const float*)d_in[8];
  float* out = (float*)d_out;
  (void)gb;

  const size_t BIG = (size_t)4 * 4096 * 512 * sizeof(f16_t);  // 16.78MB
  char* p = (char*)d_ws;
  float* mu = (float*)p; p += 2048 * sizeof(float);
  float* rs = (float*)p; p += 2048 * sizeof(float);
  float* vv = (float*)p; p += 512 * sizeof(float);
  float* uu = (float*)p; p += (size_t)4 * 4096 * sizeof(float);
  f16_t* w2 = (f16_t*)p; p += (size_t)2 * 512 * 512 * sizeof(f16_t);
  f16_t* Mh = (f16_t*)p; p += (size_t)512 * 512 * sizeof(f16_t);
  f16_t* xf = (f16_t*)p; p += BIG;
  f16_t* xc = (f16_t*)p; p += BIG;
  f16_t* Zf = (f16_t*)p; p += BIG;
  f16_t* Hv = (f16_t*)p; p += BIG;  // total ~70MB
  f16_t* Oat_t = xc;                // alias: xc dead after Hv gemm

  f16_t* whb = w2;
  f16_t* wob = w2 + 262144;

  const long sD = (long)4096 * 512;

  stats_k<<<2048, 256, 0, stream>>>(x, mu, rs);
  wcast2_k<<<512, 256, 0, stream>>>(hw, ow, w2);
  mt_k<<<dim3(8, 8), 256, 0, stream>>>(fw, gw, Mh);
  v_k<<<2, 256, 0, stream>>>(gw, fb, vv);
  normt_k<<<dim3(64, 8, 4), 256, 0, stream>>>(x, mu, rs, xf, xc);
  u_k<<<dim3(1024, 4), 256, 0, stream>>>(vv, xf, uu);
  // Z[b][n][j] = sum_i xf[n][i] * Mh[j][i]
  gemm_k<f16_t, 0, false><<<dim3(4, 32, 4), 256, 0, stream>>>(
      xf, Mh, Zf, nullptr, nullptr, nullptr, sD, 0, sD, 512);
  // Hv[b][c][n] = h_w . xc  (+h_b over c)
  gemm_k<f16_t, 1, false><<<dim3(32, 4, 4), 256, 0, stream>>>(
      whb, xc, Hv, hb, nullptr, nullptr, 0, sD, sD, 4096);
  // attention (256 blocks x 512 threads) -> Oat_t[b][q][c]
  flash_k<<<256, 512, 0, stream>>>(Zf, xf, uu, Hv, Oat_t);
  // out[b][o][n] = o_w . Oat_t^T (+o_b over o) + residual, fp32
  gemm_k<float, 1, true><<<dim3(32, 4, 4), 256, 0, stream>>>(
      wob, Oat_t, out, ob, nullptr, x, 0, sD, sD, 4096);

  (void)in_sizes; (void)n_in; (void)out_size; (void)ws_size;
}

// Round 11
// 373.372 us; speedup vs baseline: 1.5944x; 1.1043x over previous
//
#include <hip/hip_runtime.h>

// Content_SA: instance-norm -> f/g/h 1x1 convs -> attention(QK^T softmax, PV) -> o conv + residual.
// B=4, C=512, H=W=64 (N=4096).
// Algebra: energy[n,m] = xn(n)^T M xn(m) + u[m] (+ query-const, cancels in softmax), M = f_w^T g_w (fp32).
// Precision: M,Z,xn,V all f16 (single rounding from fp32-grade values); softmax fp32.
// Flash v10 = R4 skeleton (best measured: 273us; ch-half ping-pong K staging, __syncthreads,
// q=64/block, 8 waves wq4 x wk2, V reg-prefetch) + validated micro-opts only:
//   (a) u via register loads (ulds deleted), (b) defer-max THR=8, (c) P pitch 144B.
// Ten rounds of schedule variants (counted vmcnt, full-tile dbuf, anti-phase, k=128) all
// measured worse than this skeleton; qf+oacc=128 regs pins 8 waves/CU for this family.

typedef __bf16 bf16_t;
typedef _Float16 f16_t;
typedef _Float16 f16x8 __attribute__((ext_vector_type(8)));
typedef float f32x4 __attribute__((ext_vector_type(4)));

#define LOG2E 1.44269504088896340736f

__device__ __forceinline__ void gload16(const void* g, void* l) {
  __builtin_amdgcn_global_load_lds(
      (const __attribute__((address_space(1))) void*)g,
      (__attribute__((address_space(3))) void*)l, 16, 0, 0);
}

// ---------------- instance-norm statistics ----------------
__global__ void __launch_bounds__(256) stats_k(const float* __restrict__ x,
                                               float* __restrict__ mu,
                                               float* __restrict__ rs) {
  const int bc = blockIdx.x;
  const float4* row = (const float4*)(x + (size_t)bc * 4096);
  float s = 0.f, ss = 0.f;
  for (int i = threadIdx.x; i < 1024; i += 256) {
    float4 v = row[i];
    s += v.x + v.y + v.z + v.w;
    ss += v.x * v.x + v.y * v.y + v.z * v.z + v.w * v.w;
  }
#pragma unroll
  for (int o = 32; o >= 1; o >>= 1) {
    s += __shfl_down(s, o);
    ss += __shfl_down(ss, o);
  }
  __shared__ float as_[4], ass_[4];
  const int w = threadIdx.x >> 6;
  if ((threadIdx.x & 63) == 0) { as_[w] = s; ass_[w] = ss; }
  __syncthreads();
  if (threadIdx.x == 0) {
    float st = as_[0] + as_[1] + as_[2] + as_[3];
    float sst = ass_[0] + ass_[1] + ass_[2] + ass_[3];
    float m = st * (1.f / 4096.f);
    float var = sst * (1.f / 4096.f) - m * m;
    mu[bc] = m;
    rs[bc] = rsqrtf(var + 1e-5f);
  }
}

// ---------------- cast h_w, o_w fp32 -> f16 ----------------
__global__ void __launch_bounds__(256) wcast2_k(const float* __restrict__ a,
                                                const float* __restrict__ b,
                                                f16_t* __restrict__ dst) {
  const int i = blockIdx.x * 256 + threadIdx.x;
  const int which = i >> 16;
  const int off = i & 65535;
  const float* s = which ? b : a;
  const float4 v = ((const float4*)s)[off];
  alignas(8) f16_t r[4];
  r[0] = (f16_t)v.x; r[1] = (f16_t)v.y; r[2] = (f16_t)v.z; r[3] = (f16_t)v.w;
  *(uint2*)(dst + ((size_t)which << 18) + (size_t)off * 4) = *(const uint2*)r;
}

// ---------------- Mt[j][i] = sum_c f_w[c][i]*g_w[c][j], fp32 acc -> f16 ----------------
__global__ void __launch_bounds__(256) mt_k(const float* __restrict__ fw,
                                            const float* __restrict__ gw,
                                            f16_t* __restrict__ Mh) {
  __shared__ float Fs[32][64];
  __shared__ float Gs[32][64];
  const int t = threadIdx.x;
  const int it = blockIdx.x, jt = blockIdx.y;
  float acc[16];
#pragma unroll
  for (int i = 0; i < 16; ++i) acc[i] = 0.f;
  const int jl = t >> 2, ib = (t & 3) * 16;
  const int lr = t >> 4, lc4 = (t & 15) * 4;
  for (int cc = 0; cc < 16; ++cc) {
    __syncthreads();
#pragma unroll
    for (int rep = 0; rep < 2; ++rep) {
      const int r = lr + rep * 16;
      *(float4*)&Fs[r][lc4] = *(const float4*)(fw + (size_t)(cc * 32 + r) * 512 + it * 64 + lc4);
      *(float4*)&Gs[r][lc4] = *(const float4*)(gw + (size_t)(cc * 32 + r) * 512 + jt * 64 + lc4);
    }
    __syncthreads();
#pragma unroll
    for (int c = 0; c < 32; ++c) {
      const float gv = Gs[c][jl];
#pragma unroll
      for (int ii = 0; ii < 16; ++ii) acc[ii] += gv * Fs[c][ib + ii];
    }
  }
  alignas(16) f16_t hi[16];
#pragma unroll
  for (int ii = 0; ii < 16; ++ii) hi[ii] = (f16_t)acc[ii];
  const size_t o = (size_t)(jt * 64 + jl) * 512 + it * 64 + ib;
  *(uint4*)(Mh + o) = *(const uint4*)hi;
  *(uint4*)(Mh + o + 8) = *(const uint4*)(hi + 8);
}

// ---------------- v[j] = sum_c g_w[c][j] * f_b[c] ----------------
__global__ void __launch_bounds__(256) v_k(const float* __restrict__ gw,
                                           const float* __restrict__ fb,
                                           float* __restrict__ v) {
  const int j = blockIdx.x * 256 + threadIdx.x;
  float s = 0.f;
  for (int c = 0; c < 512; ++c) s += gw[(size_t)c * 512 + j] * fb[c];
  v[j] = s;
}

// ---------------- u[b][m] = v . xn(m) ----------------
__global__ void __launch_bounds__(256) u_k(const float* __restrict__ v,
                                           const f16_t* __restrict__ xf,
                                           float* __restrict__ u) {
  const int w = threadIdx.x >> 6, lane = threadIdx.x & 63;
  const int m = blockIdx.x * 4 + w;
  const int b = blockIdx.y;
  const size_t o = ((size_t)b * 4096 + m) * 512 + lane * 8;
  const f16x8 vh = *(const f16x8*)(xf + o);
  const float4 v0 = *(const float4*)(v + lane * 8);
  const float4 v1 = *(const float4*)(v + lane * 8 + 4);
  float s = 0.f;
  const float* vp = &v0.x;
#pragma unroll
  for (int e = 0; e < 4; ++e) s += (float)vh[e] * vp[e];
  const float* vq = &v1.x;
#pragma unroll
  for (int e = 0; e < 4; ++e) s += (float)vh[4 + e] * vq[e];
#pragma unroll
  for (int o2 = 32; o2 >= 1; o2 >>= 1) s += __shfl_down(s, o2);
  if (lane == 0) u[(size_t)b * 4096 + m] = s;
}

// ---------------- normalize + transpose: x[b][c][n] -> xf (norm f16), xc (raw f16) [b][n][c] ----------------
__global__ void __launch_bounds__(256) normt_k(const float* __restrict__ x,
                                               const float* __restrict__ mu,
                                               const float* __restrict__ rs,
                                               f16_t* __restrict__ xf,
                                               f16_t* __restrict__ xc) {
  __shared__ float tile[64][65];
  const int t = threadIdx.x;
  const int nt = blockIdx.x, ct = blockIdx.y, b = blockIdx.z;
  const float* src = x + ((size_t)b * 512 + ct * 64) * 4096 + nt * 64;
  {
    const int r = t >> 4, cq = (t & 15) * 4;
#pragma unroll
    for (int it = 0; it < 4; ++it) {
      const int rr = r + it * 16;
      const float4 v = *(const float4*)(src + (size_t)rr * 4096 + cq);
      tile[rr][cq] = v.x; tile[rr][cq + 1] = v.y;
      tile[rr][cq + 2] = v.z; tile[rr][cq + 3] = v.w;
    }
  }
  __syncthreads();
  const int n = t & 63, ch = t >> 6;
  alignas(16) f16_t vf[16], vc[16];
#pragma unroll
  for (int i = 0; i < 16; ++i) {
    const int c = ch * 16 + i;
    const float v = tile[c][n];
    const int gc = b * 512 + ct * 64 + c;
    vc[i] = (f16_t)v;
    vf[i] = (f16_t)((v - mu[gc]) * rs[gc]);
  }
  const size_t o = ((size_t)b * 4096 + nt * 64 + n) * 512 + ct * 64 + ch * 16;
  *(uint4*)(xf + o) = *(const uint4*)vf;
  *(uint4*)(xf + o + 8) = *(const uint4*)(vf + 8);
  *(uint4*)(xc + o) = *(const uint4*)vc;
  *(uint4*)(xc + o + 8) = *(const uint4*)(vc + 8);
}

// ---------------- f16 GEMM (double-buffered, stage-ahead): C[m][n] = A[m][k].Bt[n][k], K=512 ----------------
template <typename OT, int BIAS, bool RESID>
__global__ void __launch_bounds__(256) gemm_k(const f16_t* __restrict__ A,
                                              const f16_t* __restrict__ Bt,
                                              OT* __restrict__ C,
                                              const float* __restrict__ biasM,
                                              const float* __restrict__ biasN,
                                              const float* __restrict__ resid,
                                              long sAb, long sBb, long sCb, int ldC) {
  __shared__ alignas(16) f16_t As[2][128 * 64];
  __shared__ alignas(16) f16_t Bs[2][128 * 64];
  const int t = threadIdx.x;
  const int lane = t & 63;
  const int w = t >> 6;
  const int wr = w >> 1, wc = w & 1;
  const int l15 = lane & 15, lg = lane >> 4;
  const int b = blockIdx.z;
  const int m0 = blockIdx.y * 128, n0 = blockIdx.x * 128;
  const f16_t* Ab = A + (size_t)sAb * b + (size_t)m0 * 512;
  const f16_t* Bb = Bt + (size_t)sBb * b + (size_t)n0 * 512;
  const int srow = t >> 3;
  const int slot = t & 7;

  auto gstage = [&](int pb_, int ks_) {
#pragma unroll
    for (int r_ = 0; r_ < 4; ++r_) {
      const int rr_ = r_ * 32 + srow;
      const size_t go_ = (size_t)rr_ * 512 + ks_ * 64 + ((slot ^ (rr_ & 7)) * 8);
      gload16(Ab + go_, (char*)As[pb_] + r_ * 4096 + w * 1024);
      gload16(Bb + go_, (char*)Bs[pb_] + r_ * 4096 + w * 1024);
    }
  };

  const f32x4 z4 = {0.f, 0.f, 0.f, 0.f};
  f32x4 acc[4][4];
#pragma unroll
  for (int i = 0; i < 4; ++i)
#pragma unroll
    for (int j = 0; j < 4; ++j) acc[i][j] = z4;

  gstage(0, 0);
  __syncthreads();
  for (int ks = 0; ks < 8; ++ks) {
    const int pb = ks & 1;
    if (ks < 7) gstage(pb ^ 1, ks + 1);
#pragma unroll
    for (int kk = 0; kk < 2; ++kk) {
      f16x8 af[4], bfr[4];
#pragma unroll
      for (int i = 0; i < 4; ++i) {
        const int ra = wr * 64 + i * 16 + l15;
        af[i] = *(const f16x8*)((const char*)As[pb] + ra * 128 + (((kk * 4 + lg) ^ (ra & 7)) * 16));
        const int rb = wc * 64 + i * 16 + l15;
        bfr[i] = *(const f16x8*)((const char*)Bs[pb] + rb * 128 + (((kk * 4 + lg) ^ (rb & 7)) * 16));
      }
#pragma unroll
      for (int i = 0; i < 4; ++i)
#pragma unroll
        for (int j = 0; j < 4; ++j)
          acc[i][j] = __builtin_amdgcn_mfma_f32_16x16x32_f16(af[i], bfr[j], acc[i][j], 0, 0, 0);
    }
    __syncthreads();
  }
  OT* Cb = C + (size_t)sCb * b;
#pragma unroll
  for (int i = 0; i < 4; ++i) {
#pragma unroll
    for (int j = 0; j < 4; ++j) {
      const int n = n0 + wc * 64 + j * 16 + l15;
      float bn = 0.f;
      if (BIAS == 2) bn = biasN[n];
#pragma unroll
      for (int r = 0; r < 4; ++r) {
        const int m = m0 + wr * 64 + i * 16 + lg * 4 + r;
        float v = acc[i][j][r] + bn;
        if (BIAS == 1) v += biasM[m];
        if (RESID) v += resid[(size_t)sCb * b + (size_t)m * ldC + n];
        Cb[(size_t)m * ldC + n] = (OT)v;
      }
    }
  }
}

// ---------------- flash attention v10: R4 skeleton + u-regs + defer-max + P144 ----------------
// Q=Z[b][q][c] f16 in regs; K=xf[b][k][c] f16, LDS ch-half ping-pong (2x32KB); V=Hv[b][c][k]
// reg-prefetch; out Oat_t[b][q][c]. 8 waves: wq=w&3 (16 q), wk=w>>2 (32 keys). 64 tiles.
__global__ void __launch_bounds__(512, 1) flash_k(const f16_t* __restrict__ Z,
                                                  const f16_t* __restrict__ X,
                                                  const float* __restrict__ u,
                                                  const f16_t* __restrict__ Hv,
                                                  f16_t* __restrict__ Oat_t) {
  __shared__ alignas(16) f16_t K[2][64 * 256];  // 2 x 32KB, 512B rows, slot-swizzled
  __shared__ alignas(16) f16_t P[64 * 72];      // 9KB, 144B rows (2-way bank alias = free)
  __shared__ float redm[4][2][16];
  __shared__ float reds[4][2][16];
  __shared__ float alds[64];
  __shared__ float llds[64];

  const int t = threadIdx.x;
  const int lane = t & 63;
  const int w = t >> 6;
  const int wq = w & 3, wk = w >> 2;
  const int l15 = lane & 15, lg = lane >> 4;
  const int bid = blockIdx.x;
  const int xcd = bid & 7;
  const int b = xcd >> 1;
  const int q0 = ((xcd & 1) * 32 + (bid >> 3)) * 64;

  const f16_t* Kb = X + (size_t)b * 4096 * 512;
  const f16_t* Vb = Hv + (size_t)b * 512 * 4096;
  const float* ub = u + (size_t)b * 4096;

  const int srow = w * 2 + (lane >> 5);
  const int slot32 = lane & 31;

  auto stagek = [&](int pb_, int kt_, int hf_) {
    const int k0_ = kt_ * 64;
#pragma unroll
    for (int r_ = 0; r_ < 4; ++r_) {
      const int row_ = r_ * 16 + srow;
      const size_t go_ = (size_t)(k0_ + row_) * 512 + hf_ * 256 + ((slot32 ^ (row_ & 7)) * 8);
      gload16(Kb + go_, (char*)K[pb_] + r_ * 8192 + w * 1024);
    }
  };

// QK on buffer PB, channel-half HF: 16 MFMA
#define QKHALF(PB, HF)                                                                        \
  do {                                                                                        \
    _Pragma("unroll") for (int cwl_ = 0; cwl_ < 8; ++cwl_) {                                  \
      const f16x8 qf_ = qf[(HF) * 8 + cwl_];                                                  \
      _Pragma("unroll") for (int mf_ = 0; mf_ < 2; ++mf_) {                                   \
        const int key_ = 32 * wk + 16 * mf_ + l15;                                            \
        const int so_ = ((cwl_ * 4 + lg) ^ (key_ & 7)) * 16;                                  \
        const f16x8 kf_ = *(const f16x8*)((const char*)K[PB] + key_ * 512 + so_);             \
        sacc[mf_] = __builtin_amdgcn_mfma_f32_16x16x32_f16(kf_, qf_, sacc[mf_], 0, 0, 0);     \
      }                                                                                       \
    }                                                                                         \
  } while (0)

  // Q fragments in registers: q = q0 + 16*wq + l15, ch window cw*32 + lg*8
  f16x8 qf[16];
  {
    const size_t qo = ((size_t)b * 4096 + q0 + 16 * wq + l15) * 512 + lg * 8;
#pragma unroll
    for (int cw = 0; cw < 16; ++cw) qf[cw] = *(const f16x8*)(Z + qo + cw * 32);
  }
  stagek(0, 0, 0);

  const f32x4 z4 = {0.f, 0.f, 0.f, 0.f};
  f32x4 oacc[4][4];
#pragma unroll
  for (int i = 0; i < 4; ++i)
#pragma unroll
    for (int j = 0; j < 4; ++j) oacc[i][j] = z4;
  float m_run = -3.0e38f, l_run = 0.f;
  const int qrow = 16 * wq + l15;

  __syncthreads();  // buf0.half0 ready

  for (int kt = 0; kt < 64; ++kt) {
    const int k0 = kt * 64;
    f32x4 sacc[2] = {z4, z4};
    // u for this wave's 32 keys (register loads; drained at sync1 like everything else)
    const float4 u0 = *(const float4*)(ub + k0 + 32 * wk + 4 * lg);
    const float4 u1 = *(const float4*)(ub + k0 + 32 * wk + 16 + 4 * lg);
    stagek(1, kt, 1);  // half1 -> buf1, flies under QK0
    QKHALF(0, 0);
    __syncthreads();   // buf1 ready
    if (kt < 63) stagek(0, kt + 1, 0);  // next half0 -> buf0, flies under QK1+softmax
    // V prefetch for this tile
    f16x8 vpre[4][2];
#pragma unroll
    for (int ct = 0; ct < 4; ++ct) {
      const int c = 64 * w + 16 * ct + l15;
#pragma unroll
      for (int kk = 0; kk < 2; ++kk)
        vpre[ct][kk] = *(const f16x8*)(Vb + (size_t)c * 4096 + k0 + kk * 32 + lg * 8);
    }
    QKHALF(1, 1);
    // ---- u bias + per-lane max ----
    float pm = -3.0e38f;
    {
      const float* up0 = &u0.x;
      const float* up1 = &u1.x;
#pragma unroll
      for (int j = 0; j < 4; ++j) {
        sacc[0][j] += up0[j];
        sacc[1][j] += up1[j];
        pm = fmaxf(pm, fmaxf(sacc[0][j], sacc[1][j]));
      }
    }
    pm = fmaxf(pm, __shfl_xor(pm, 16));
    pm = fmaxf(pm, __shfl_xor(pm, 32));
    if (lane < 16) redm[wq][wk][lane] = pm;
    __syncthreads();
    // ---- softmax with defer-max (THR=8) ----
    const float m_tile = fmaxf(pm, redm[wq][wk ^ 1][l15]);
    float alpha;
    if (m_tile > m_run + 8.f) {
      alpha = exp2f((m_run - m_tile) * LOG2E);
      m_run = m_tile;
    } else {
      alpha = 1.f;
    }
    float ps = 0.f;
    {
      alignas(8) f16_t pk[4];
#pragma unroll
      for (int mf = 0; mf < 2; ++mf) {
#pragma unroll
        for (int j = 0; j < 4; ++j) {
          const float p = exp2f((sacc[mf][j] - m_run) * LOG2E);
          ps += p;
          pk[j] = (f16_t)p;
        }
        *(uint2*)((char*)P + qrow * 144 + 64 * wk + 32 * mf + 8 * lg) = *(const uint2*)pk;
      }
    }
    ps += __shfl_xor(ps, 16);
    ps += __shfl_xor(ps, 32);
    if (lane < 16) {
      reds[wq][wk][lane] = ps;
      if (wk == 0) alds[16 * wq + lane] = alpha;
    }
    __syncthreads();  // P / reds / alds ready
    const float s_tile = reds[wq][0][l15] + reds[wq][1][l15];
    l_run = l_run * alpha + s_tile;
    // ---- rescale (skippable) + PV: oacc[c][q] += V[c][k] * P[q][k] ----
    float aq[4];
#pragma unroll
    for (int qt = 0; qt < 4; ++qt) aq[qt] = alds[16 * qt + l15];
    const bool need = (aq[0] != 1.f) || (aq[1] != 1.f) || (aq[2] != 1.f) || (aq[3] != 1.f);
    if (__any(need)) {
#pragma unroll
      for (int ct = 0; ct < 4; ++ct)
#pragma unroll
        for (int qt = 0; qt < 4; ++qt) oacc[ct][qt] *= aq[qt];
    }
#pragma unroll
    for (int kk = 0; kk < 2; ++kk) {
      f16x8 bp[4];
#pragma unroll
      for (int qt = 0; qt < 4; ++qt) {
        const int q = 16 * qt + l15;
        bp[qt] = *(const f16x8*)((const char*)P + q * 144 + kk * 64 + lg * 16);
      }
#pragma unroll
      for (int ct = 0; ct < 4; ++ct)
#pragma unroll
        for (int qt = 0; qt < 4; ++qt)
          oacc[ct][qt] =
              __builtin_amdgcn_mfma_f32_16x16x32_f16(vpre[ct][kk], bp[qt], oacc[ct][qt], 0, 0, 0);
    }
  }
#undef QKHALF
  // ---- epilogue: divide by l, store transposed [q][c] ----
  if (wk == 0 && lane < 16) llds[16 * wq + lane] = l_run;
  __syncthreads();
  float inv[4];
#pragma unroll
  for (int qt = 0; qt < 4; ++qt) inv[qt] = 1.f / llds[16 * qt + l15];
#pragma unroll
  for (int ct = 0; ct < 4; ++ct)
#pragma unroll
    for (int qt = 0; qt < 4; ++qt) {
      alignas(8) f16_t o4[4];
#pragma unroll
      for (int j = 0; j < 4; ++j) o4[j] = (f16_t)(oacc[ct][qt][j] * inv[qt]);
      *(uint2*)(Oat_t + ((size_t)b * 4096 + q0 + 16 * qt + l15) * 512 + 64 * w + 16 * ct + 4 * lg) =
          *(const uint2*)o4;
    }
}

// ---------------- host launch ----------------
extern "C" void kernel_launch(void* const* d_in, const int* in_sizes, int n_in,
                              void* d_out, int out_size, void* d_ws, size_t ws_size,
                              hipStream_t stream) {
  const float* x = (const float*)d_in[0];
  const float* fw = (const float*)d_in[1];
  const float* fb = (const float*)d_in[2];
  const float* gw = (const float*)d_in[3];
  const float* gb = (const float*)d_in[4];
  const float* hw = (const float*)d_in[5];
  const float* hb = (const float*)d_in[6];
  const float* ow = (const float*)d_in[7];
  const float* ob = (const float*)d_in[8];
  float* out = (float*)d_out;
  (void)gb;

  const size_t BIG = (size_t)4 * 4096 * 512 * sizeof(f16_t);  // 16.78MB
  char* p = (char*)d_ws;
  float* mu = (float*)p; p += 2048 * sizeof(float);
  float* rs = (float*)p; p += 2048 * sizeof(float);
  float* vv = (float*)p; p += 512 * sizeof(float);
  float* uu = (float*)p; p += (size_t)4 * 4096 * sizeof(float);
  f16_t* w2 = (f16_t*)p; p += (size_t)2 * 512 * 512 * sizeof(f16_t);
  f16_t* Mh = (f16_t*)p; p += (size_t)512 * 512 * sizeof(f16_t);
  f16_t* xf = (f16_t*)p; p += BIG;
  f16_t* xc = (f16_t*)p; p += BIG;
  f16_t* Zf = (f16_t*)p; p += BIG;
  f16_t* Hv = (f16_t*)p; p += BIG;  // total ~70MB
  f16_t* Oat_t = xc;                // alias: xc dead after Hv gemm

  f16_t* whb = w2;
  f16_t* wob = w2 + 262144;

  const long sD = (long)4096 * 512;

  stats_k<<<2048, 256, 0, stream>>>(x, mu, rs);
  wcast2_k<<<512, 256, 0, stream>>>(hw, ow, w2);
  mt_k<<<dim3(8, 8), 256, 0, stream>>>(fw, gw, Mh);
  v_k<<<2, 256, 0, stream>>>(gw, fb, vv);
  normt_k<<<dim3(64, 8, 4), 256, 0, stream>>>(x, mu, rs, xf, xc);
  u_k<<<dim3(1024, 4), 256, 0, stream>>>(vv, xf, uu);
  // Z[b][n][j] = sum_i xf[n][i] * Mh[j][i]
  gemm_k<f16_t, 0, false><<<dim3(4, 32, 4), 256, 0, stream>>>(
      xf, Mh, Zf, nullptr, nullptr, nullptr, sD, 0, sD, 512);
  // Hv[b][c][n] = h_w . xc  (+h_b over c)
  gemm_k<f16_t, 1, false><<<dim3(32, 4, 4), 256, 0, stream>>>(
      whb, xc, Hv, hb, nullptr, nullptr, 0, sD, sD, 4096);
  // attention (256 blocks x 512 threads) -> Oat_t[b][q][c]
  flash_k<<<256, 512, 0, stream>>>(Zf, xf, uu, Hv, Oat_t);
  // out[b][o][n] = o_w . Oat_t^T (+o_b over o) + residual, fp32
  gemm_k<float, 1, true><<<dim3(32, 4, 4), 256, 0, stream>>>(
      wob, Oat_t, out, ob, nullptr, x, 0, sD, sD, 4096);

  (void)in_sizes; (void)n_in; (void)out_size; (void)ws_size;
}